// Round 4
// baseline (62.613 us; speedup 1.0000x reference)
//
#include <hip/hip_runtime.h>

#define KDIM   128
#define BM     64
#define NELEM  8388608
#define FSTR   144     // latent staging stride (elements)

// LDS layout (bytes):
// [0,32768)      mbuf float[64][16][8]   (fLds ushort[64][144]=18432B aliases it during setup)
// [32768,36864)  esqmLds f32[1024]       (-0.5*||e||^2)
// [36864,37120)  fsqLds f32[64]
// [37120,37376)  selLds i32[64]
#define OFF_ESQ 32768
#define OFF_FSQ 36864
#define OFF_SEL 37120
#define SMEM_SZ 37376

typedef __attribute__((ext_vector_type(8)))  short  short8;
typedef __attribute__((ext_vector_type(8)))  __bf16 bf16x8;
typedef __attribute__((ext_vector_type(4)))  float  f32x4;

__device__ inline ushort f2bf(float f) {            // RNE fp32 -> bf16
  unsigned u = __builtin_bit_cast(unsigned, f);
  u += 0x7fffu + ((u >> 16) & 1u);
  return (ushort)(u >> 16);
}
__device__ inline f32x4 mfma16(short8 a, short8 b, f32x4 c) {
  return __builtin_amdgcn_mfma_f32_16x16x32_bf16(
      __builtin_bit_cast(bf16x8, a), __builtin_bit_cast(bf16x8, b), c, 0, 0, 0);
}

// ---- prep: embedding fp32 -> bf16 (row-major, no swizzle) + -0.5*||e||^2 ----
__global__ void vq_prep(const float* __restrict__ emb, ushort* __restrict__ ebf,
                        float* __restrict__ esqm) {
  int j = blockIdx.x, d = threadIdx.x;              // 1024 x 128
  float v = emb[j * KDIM + d];
  ebf[j * KDIM + d] = f2bf(v);
  float s = v * v;
#pragma unroll
  for (int m = 1; m <= 32; m <<= 1) s += __shfl_xor(s, m);
  __shared__ float w[2];
  if ((threadIdx.x & 63) == 0) w[threadIdx.x >> 6] = s;
  __syncthreads();
  if (threadIdx.x == 0) esqm[j] = -0.5f * (w[0] + w[1]);
}

// ---- main: codes-from-L2, latents-in-registers, barrier-free main loop ----
__global__ __launch_bounds__(256, 2) void vq_main(
    const float* __restrict__ lat, const float* __restrict__ emb,
    const int* __restrict__ ksel, const ushort* __restrict__ ebf,
    const float* __restrict__ esqm, float* __restrict__ out,
    float* __restrict__ partial) {
  __shared__ __align__(16) unsigned char smem[SMEM_SZ];
  ushort* fLds    = (ushort*)(smem);
  float*  mbuf    = (float*)(smem);
  float*  esqmLds = (float*)(smem + OFF_ESQ);
  float*  fsqLds  = (float*)(smem + OFF_FSQ);
  int*    selLds  = (int*)(smem + OFF_SEL);

  const int tid = threadIdx.x;
  const int lane = tid & 63, wid = tid >> 6;
  const int gR0 = blockIdx.x * BM;

  // all 1024 pre-scaled code norms -> LDS
  ((float4*)esqmLds)[tid] = ((const float4*)esqm)[tid];

  // stage latents (bf16) to LDS + per-row ||f||^2
#pragma unroll
  for (int it = 0; it < 8; ++it) {
    int i = tid + it * 256;
    int row = i >> 5, c4 = i & 31;
    float4 v = *(const float4*)(lat + (size_t)(gR0 + row) * KDIM + c4 * 4);
    float s = v.x * v.x + v.y * v.y + v.z * v.z + v.w * v.w;
#pragma unroll
    for (int m = 1; m <= 16; m <<= 1) s += __shfl_xor(s, m);
    if ((lane & 31) == 0) fsqLds[row] = s;
    ushort4 b; b.x = f2bf(v.x); b.y = f2bf(v.y); b.z = f2bf(v.z); b.w = f2bf(v.w);
    *(ushort4*)(&fLds[row * FSTR + c4 * 4]) = b;
  }
  __syncthreads();

  const int n = lane & 15, hi = lane >> 4;
  // B-operand: ALL 64 latent rows of the block, in registers (16 frags)
  short8 bfr[4][4];
#pragma unroll
  for (int ct = 0; ct < 4; ++ct)
#pragma unroll
    for (int s = 0; s < 4; ++s)
      bfr[ct][s] = *(const short8*)(&fLds[(ct * 16 + n) * FSTR + s * 32 + hi * 8]);
  __syncthreads();          // fLds dead after this; mbuf region reusable

  // wave's 256-code range; lane reads row (c0 + u*16 + n), k = s*32 + hi*8
  const ushort* aBase = ebf + ((size_t)(wid * 256 + n) * KDIM) + hi * 8;

  const float NINF = __builtin_bit_cast(float, 0xFF800000u);
  float top[4][8];
#pragma unroll
  for (int ct = 0; ct < 4; ++ct)
#pragma unroll
    for (int p = 0; p < 8; ++p) top[ct][p] = NINF;

  short8 afr[2][8];
#pragma unroll
  for (int u = 0; u < 2; ++u)
#pragma unroll
    for (int s = 0; s < 4; ++s)
      afr[0][u * 4 + s] = *(const short8*)(aBase + u * 16 * KDIM + s * 32);

#pragma unroll
  for (int tp = 0; tp < 8; ++tp) {
    // prefetch next tile-pair's A fragments (regs; latency hides under MFMA+select)
    if (tp < 7) {
      const ushort* ap = aBase + (size_t)(tp + 1) * 32 * KDIM;
#pragma unroll
      for (int u = 0; u < 2; ++u)
#pragma unroll
        for (int s = 0; s < 4; ++s)
          afr[(tp + 1) & 1][u * 4 + s] = *(const short8*)(ap + u * 16 * KDIM + s * 32);
    }
    // acc init = -0.5||e||^2 => final = f.e - ||e||^2/2 (maximize)
    f32x4 acc[2][4];
#pragma unroll
    for (int u = 0; u < 2; ++u) {
      f32x4 e = *(const f32x4*)(esqmLds + wid * 256 + tp * 32 + u * 16 + hi * 4);
#pragma unroll
      for (int ct = 0; ct < 4; ++ct) acc[u][ct] = e;
    }
#pragma unroll
    for (int s = 0; s < 4; ++s)
#pragma unroll
      for (int u = 0; u < 2; ++u)
#pragma unroll
        for (int ct = 0; ct < 4; ++ct)
          acc[u][ct] = mfma16(afr[tp & 1][u * 4 + s], bfr[ct][s], acc[u][ct]);

    // selection: pack code id into low-10 mantissa bits, 8-way tree max, insert
    const int cbase = wid * 256 + tp * 32 + hi * 4;
#pragma unroll
    for (int ct = 0; ct < 4; ++ct) {
      float k[8];
#pragma unroll
      for (int u = 0; u < 2; ++u)
#pragma unroll
        for (int r = 0; r < 4; ++r) {
          unsigned bb = (__builtin_bit_cast(unsigned, acc[u][ct][r]) & 0xFFFFFC00u)
                        | (unsigned)(cbase + u * 16 + r);
          k[u * 4 + r] = __builtin_bit_cast(float, bb);
        }
      float x = fmaxf(fmaxf(k[0], k[1]), k[2]);
      float y = fmaxf(fmaxf(k[3], k[4]), k[5]);
      float key = fmaxf(fmaxf(x, y), fmaxf(k[6], k[7]));
#pragma unroll
      for (int p = 0; p < 8; ++p) {           // descending top-8, branchless
        float mx = fmaxf(top[ct][p], key);
        key = fminf(top[ct][p], key);
        top[ct][p] = mx;
      }
    }
  }

  // dump lists: latent L=ct*16+n gets 16 lists (wid*4+hi), slot XOR'd by n (4-way banks)
#pragma unroll
  for (int ct = 0; ct < 4; ++ct) {
    float* dst = mbuf + ((size_t)((ct * 16 + n) * 16 + ((wid * 4 + hi) ^ n))) * 8;
    *(f32x4*)(dst + 0) = (f32x4){top[ct][0], top[ct][1], top[ct][2], top[ct][3]};
    *(f32x4*)(dst + 4) = (f32x4){top[ct][4], top[ct][5], top[ct][6], top[ct][7]};
  }
  __syncthreads();

  // merge 16 sorted lists per latent, pick k-th (keys globally unique via index bits)
  if (tid < 64) {
    const int L = tid, nx = L & 15;
    int kk = ksel[L & 7]; kk = kk < 0 ? 0 : (kk > 7 ? 7 : kk);
    float h[16]; int ix[16];
#pragma unroll
    for (int j = 0; j < 16; ++j) { h[j] = mbuf[(L * 16 + (j ^ nx)) * 8]; ix[j] = 0; }
    float sel;
    for (int s = 0;; ++s) {
      float m01 = fmaxf(fmaxf(h[0], h[1]), fmaxf(h[2], h[3]));
      float m23 = fmaxf(fmaxf(h[4], h[5]), fmaxf(h[6], h[7]));
      float m45 = fmaxf(fmaxf(h[8], h[9]), fmaxf(h[10], h[11]));
      float m67 = fmaxf(fmaxf(h[12], h[13]), fmaxf(h[14], h[15]));
      sel = fmaxf(fmaxf(m01, m23), fmaxf(m45, m67));
      if (s == kk) break;
#pragma unroll
      for (int j = 0; j < 16; ++j) {
        if (h[j] == sel) {
          ++ix[j];
          h[j] = (ix[j] < 8) ? mbuf[(L * 16 + (j ^ nx)) * 8 + ix[j]] : NINF;
        }
      }
    }
    unsigned sb = __builtin_bit_cast(unsigned, sel);
    selLds[L] = (int)(sb & 1023u);
    // row loss = ||f||^2 - 2*(f.e - ||e||^2/2) = ||q - f||^2
    float val = __builtin_bit_cast(float, sb & 0xFFFFFC00u);
    float rl = fsqLds[L] - 2.0f * val;
#pragma unroll
    for (int m = 1; m <= 32; m <<= 1) rl += __shfl_xor(rl, m);
    if (L == 0) partial[blockIdx.x] = rl;
  }
  __syncthreads();

  // epilogue: gather selected fp32 code rows -> out (coalesced; emb is L2-hot)
#pragma unroll
  for (int it = 0; it < 8; ++it) {
    int i = tid + it * 256;
    int row = i >> 5, c4 = i & 31;
    int s2 = selLds[row];
    float4 q = *(const float4*)(emb + (size_t)s2 * KDIM + c4 * 4);
    *(float4*)(out + (size_t)(gR0 + row) * KDIM + c4 * 4) = q;
  }
}

// ---- deterministic loss reduction over 1024 block partials ----
__global__ void vq_reduce(const float* __restrict__ p, float* __restrict__ loss) {
  int t = threadIdx.x;
  double s = (double)p[t] + (double)p[t + 256] + (double)p[t + 512] + (double)p[t + 768];
#pragma unroll
  for (int m = 1; m <= 32; m <<= 1) s += __shfl_xor(s, m);
  __shared__ double w[4];
  if ((t & 63) == 0) w[t >> 6] = s;
  __syncthreads();
  if (t == 0) loss[0] = (float)((w[0] + w[1] + w[2] + w[3]) * (1.25 / 8388608.0));
}

extern "C" void kernel_launch(void* const* d_in, const int* in_sizes, int n_in,
                              void* d_out, int out_size, void* d_ws, size_t ws_size,
                              hipStream_t stream) {
  const float* lat = (const float*)d_in[0];   // [65536 x 128] fp32 (viewed flat)
  const float* emb = (const float*)d_in[1];   // [1024 x 128]  fp32
  const int* ksel = (const int*)d_in[2];      // [8] int32
  float* out = (float*)d_out;                 // quantized[8388608] + loss[1]

  ushort* ebf = (ushort*)d_ws;                          // 262144 B (bf16 codes, row-major)
  float* esqm = (float*)((char*)d_ws + 262144);         // 4096 B (-0.5*||e||^2)
  float* partial = (float*)((char*)d_ws + 266240);      // 4096 B

  vq_prep<<<1024, 128, 0, stream>>>(emb, ebf, esqm);
  vq_main<<<1024, 256, 0, stream>>>(lat, emb, ksel, ebf, esqm, out, partial);
  vq_reduce<<<1, 256, 0, stream>>>(partial, out + NELEM);
}

// Round 5
// 45.947 us; speedup vs baseline: 1.3627x; 1.3627x over previous
//
#include <hip/hip_runtime.h>

#define KDIM   128
#define BM     128
#define NELEM  8388608

// LDS layout (bytes):
// [0,36864)      fLds ushort[128][144]   (ebuf1 aliases [0,16384); mbuf f32[128][68] aliases [0,34816))
// [36864,40960)  esqmLds f32[1024]       (-0.5*||e||^2)
// [40960,57344)  ebuf0 (16384)
// [57344,57856)  fsqLds f32[128]
// [57856,58368)  selLds i32[128]
// [58368,58376)  redL f32[2]
#define OFF_ESQ   36864
#define OFF_EBUF0 40960
#define OFF_FSQ   57344
#define OFF_SEL   57856
#define OFF_RED   58368
#define SMEM_SZ   58400

typedef __attribute__((ext_vector_type(8)))  short  short8;
typedef __attribute__((ext_vector_type(8)))  __bf16 bf16x8;
typedef __attribute__((ext_vector_type(4)))  float  f32x4;

__device__ inline ushort f2bf(float f) {            // RNE fp32 -> bf16
  unsigned u = __builtin_bit_cast(unsigned, f);
  u += 0x7fffu + ((u >> 16) & 1u);
  return (ushort)(u >> 16);
}
__device__ inline f32x4 mfma16(short8 a, short8 b, f32x4 c) {
  return __builtin_amdgcn_mfma_f32_16x16x32_bf16(
      __builtin_bit_cast(bf16x8, a), __builtin_bit_cast(bf16x8, b), c, 0, 0, 0);
}
__device__ inline void gload16(const void* g, void* l) {
  __builtin_amdgcn_global_load_lds(
      (const __attribute__((address_space(1))) unsigned*)g,
      (__attribute__((address_space(3))) unsigned*)l, 16, 0, 0);
}

// ---- prep: embedding fp32 -> bf16 (K-XOR-swizzled) + per-code -0.5*||e||^2 ----
__global__ void vq_prep(const float* __restrict__ emb, ushort* __restrict__ ebf,
                        float* __restrict__ esqm) {
  int j = blockIdx.x, d = threadIdx.x;              // 1024 x 128
  float v = emb[j * KDIM + d];
  ebf[j * KDIM + (d ^ ((j & 7) << 3))] = f2bf(v);   // elem-XOR == byte ^ ((row&7)<<4)
  float s = v * v;
#pragma unroll
  for (int m = 1; m <= 32; m <<= 1) s += __shfl_xor(s, m);
  __shared__ float w[2];
  if ((threadIdx.x & 63) == 0) w[threadIdx.x >> 6] = s;
  __syncthreads();
  if (threadIdx.x == 0) esqm[j] = -0.5f * (w[0] + w[1]);
}

// ---- main: BM=128, wave = (latent-group, code-half), LDS dbuf codes ----
__global__ __launch_bounds__(256, 2) void vq_main(
    const float* __restrict__ lat, const float* __restrict__ emb,
    const int* __restrict__ ksel, const ushort* __restrict__ ebf,
    const float* __restrict__ esqm, float* __restrict__ out,
    float* __restrict__ partial) {
  __shared__ __align__(16) unsigned char smem[SMEM_SZ];
  ushort* fLds    = (ushort*)(smem);
  float*  mbuf    = (float*)(smem);
  float*  esqmLds = (float*)(smem + OFF_ESQ);
  float*  fsqLds  = (float*)(smem + OFF_FSQ);
  int*    selLds  = (int*)(smem + OFF_SEL);
  float*  redL    = (float*)(smem + OFF_RED);

  const int tid = threadIdx.x;
  const int lane = tid & 63, wid = tid >> 6;
  const int gR0 = blockIdx.x * BM;

  // prefetch code-chunk 0 -> ebuf0 (ebf pre-swizzled; linear copy)
  {
    const char* src = (const char*)ebf + tid * 16;
    char* dst = (char*)smem + OFF_EBUF0 + tid * 16;
#pragma unroll
    for (int q = 0; q < 4; ++q) gload16(src + q * 4096, dst + q * 4096);
  }
  // all 1024 pre-scaled code norms -> LDS
  ((float4*)esqmLds)[tid] = ((const float4*)esqm)[tid];

  // stage 128 latents (bf16) + per-row ||f||^2
#pragma unroll
  for (int it = 0; it < 16; ++it) {
    int i = tid + it * 256;
    int row = i >> 5, c4 = i & 31;
    float4 v = *(const float4*)(lat + (size_t)(gR0 + row) * KDIM + c4 * 4);
    float s = v.x * v.x + v.y * v.y + v.z * v.z + v.w * v.w;
#pragma unroll
    for (int m = 1; m <= 16; m <<= 1) s += __shfl_xor(s, m);
    if ((i & 31) == 0) fsqLds[row] = s;
    ushort4 b; b.x = f2bf(v.x); b.y = f2bf(v.y); b.z = f2bf(v.z); b.w = f2bf(v.w);
    *(ushort4*)(&fLds[row * 144 + c4 * 4]) = b;
  }
  __syncthreads();

  const int n = lane & 15, hi = lane >> 4;
  const int g = wid >> 1, h = wid & 1;
  // B-operand: this wave's 64 latent rows, resident in registers (16 frags)
  short8 bfr[4][4];
#pragma unroll
  for (int ct = 0; ct < 4; ++ct)
#pragma unroll
    for (int s = 0; s < 4; ++s)
      bfr[ct][s] = *(const short8*)(&fLds[(g * 64 + ct * 16 + n) * 144 + s * 32 + hi * 8]);
  asm volatile("s_waitcnt lgkmcnt(0)" ::: "memory");  // frags read before ebuf1 overwrites

  // A-read addressing (swizzled): byte = rowb + [(s*64+hi*16) ^ ((n&7)<<4)] + t*4096
  const int pb = ((hi ^ (n & 3)) << 4) | (((n >> 2) & 1) << 6);
  const int rowb = h * 8192 + n * 256;
  const char* aE0 = (const char*)smem + OFF_EBUF0 + rowb + pb;
  const char* aO0 = (const char*)smem + OFF_EBUF0 + rowb + (pb ^ 64);
  const char* aE1 = (const char*)smem + 0 + rowb + pb;
  const char* aO1 = (const char*)smem + 0 + rowb + (pb ^ 64);

  int cst[2][4];
#pragma unroll
  for (int t = 0; t < 2; ++t)
#pragma unroll
    for (int r = 0; r < 4; ++r) cst[t][r] = h * 32 + t * 16 + hi * 4 + r;

  const float NINF = __builtin_bit_cast(float, 0xFF800000u);
  float top[4][8];
#pragma unroll
  for (int ct = 0; ct < 4; ++ct)
#pragma unroll
    for (int p = 0; p < 8; ++p) top[ct][p] = NINF;

#pragma unroll 2
  for (int nn = 0; nn < 16; ++nn) {
    __builtin_amdgcn_s_barrier();            // prev-buffer reads done -> overwritable
    if (nn < 15) {
      const char* src = (const char*)ebf + (nn + 1) * 16384 + tid * 16;
      char* dst = (char*)smem + ((nn & 1) ? OFF_EBUF0 : 0) + tid * 16;
#pragma unroll
      for (int q = 0; q < 4; ++q) gload16(src + q * 4096, dst + q * 4096);
      asm volatile("s_waitcnt vmcnt(4)" ::: "memory");   // my cur-chunk loads landed
    } else {
      asm volatile("s_waitcnt vmcnt(0)" ::: "memory");
    }
    __builtin_amdgcn_s_barrier();            // everyone's cur-chunk writes landed

    const char* aEb = (nn & 1) ? aE1 : aE0;
    const char* aOb = (nn & 1) ? aO1 : aO0;

    // acc init = -0.5*||e||^2  => final = f.e - ||e||^2/2 (maximize)
    f32x4 acc[2][4];
#pragma unroll
    for (int t = 0; t < 2; ++t) {
      f32x4 e = *(const f32x4*)(esqmLds + nn * 64 + h * 32 + t * 16 + hi * 4);
#pragma unroll
      for (int ct = 0; ct < 4; ++ct) acc[t][ct] = e;
    }
#pragma unroll
    for (int s = 0; s < 4; ++s) {
      const char* ab = (s & 1) ? aOb : aEb;
      const int so = (s >> 1) * 128;
      short8 a0 = *(const short8*)(ab + so);
      short8 a1 = *(const short8*)(ab + 4096 + so);
#pragma unroll
      for (int ct = 0; ct < 4; ++ct) {
        acc[0][ct] = mfma16(a0, bfr[ct][s], acc[0][ct]);
        acc[1][ct] = mfma16(a1, bfr[ct][s], acc[1][ct]);
      }
    }

    // selection: pack 6-bit local id into mantissa, 8-way tree max, insert
#pragma unroll
    for (int ct = 0; ct < 4; ++ct) {
      float k[8];
#pragma unroll
      for (int t = 0; t < 2; ++t)
#pragma unroll
        for (int r = 0; r < 4; ++r) {
          unsigned bb = (__builtin_bit_cast(unsigned, acc[t][ct][r]) & 0xFFFFFC00u)
                        | (unsigned)cst[t][r];
          k[t * 4 + r] = __builtin_bit_cast(float, bb);
        }
      float x = fmaxf(fmaxf(k[0], k[1]), k[2]);
      float y = fmaxf(fmaxf(k[3], k[4]), k[5]);
      float c = fmaxf(fmaxf(x, y), fmaxf(k[6], k[7]));
      unsigned cb = __builtin_bit_cast(unsigned, c) | (unsigned)(nn << 6);
      float key = __builtin_bit_cast(float, cb);
#pragma unroll
      for (int p = 0; p < 8; ++p) {           // descending top-8, branchless
        float mx = fmaxf(top[ct][p], key);
        key = fminf(top[ct][p], key);
        top[ct][p] = mx;
      }
    }
  }

  __syncthreads();   // chunk-15 reads done; mbuf region reusable

  // dump: latent L gets 8 lists (h*4+hi), slot XOR'd by n&7; stride 68 floats
#pragma unroll
  for (int ct = 0; ct < 4; ++ct) {
    const int L = g * 64 + ct * 16 + n;
    const int sl = (h * 4 + hi) ^ (n & 7);
    float* dst = mbuf + L * 68 + sl * 8;
    *(f32x4*)(dst + 0) = (f32x4){top[ct][0], top[ct][1], top[ct][2], top[ct][3]};
    *(f32x4*)(dst + 4) = (f32x4){top[ct][4], top[ct][5], top[ct][6], top[ct][7]};
  }
  __syncthreads();

  // merge 8 sorted lists per latent, pick k-th (keys unique via id bits)
  if (tid < 128) {
    const int L = tid, xk = L & 7;
    int kk = ksel[L & 7]; kk = kk < 0 ? 0 : (kk > 7 ? 7 : kk);
    float hh[8]; int ix[8];
#pragma unroll
    for (int j = 0; j < 8; ++j) { hh[j] = mbuf[L * 68 + ((j ^ xk) << 3)]; ix[j] = 0; }
    float sel;
    for (int s = 0;; ++s) {
      float m01 = fmaxf(fmaxf(hh[0], hh[1]), fmaxf(hh[2], hh[3]));
      float m23 = fmaxf(fmaxf(hh[4], hh[5]), fmaxf(hh[6], hh[7]));
      sel = fmaxf(m01, m23);
      if (s == kk) break;
#pragma unroll
      for (int j = 0; j < 8; ++j) {
        if (hh[j] == sel) {
          ++ix[j];
          hh[j] = (ix[j] < 8) ? mbuf[L * 68 + ((j ^ xk) << 3) + ix[j]] : NINF;
        }
      }
    }
    unsigned sb = __builtin_bit_cast(unsigned, sel);
    selLds[L] = (int)(sb & 1023u);
    // row loss = ||f||^2 - 2*(f.e - ||e||^2/2) = ||q - f||^2
    float val = __builtin_bit_cast(float, sb & 0xFFFFFC00u);
    float rl = fsqLds[L] - 2.0f * val;
#pragma unroll
    for (int m = 1; m <= 32; m <<= 1) rl += __shfl_xor(rl, m);
    if (lane == 0) redL[wid] = rl;
  }
  __syncthreads();
  if (tid == 0) partial[blockIdx.x] = redL[0] + redL[1];

  // epilogue: gather selected fp32 code rows -> out (coalesced; emb L2-hot)
#pragma unroll
  for (int it = 0; it < 16; ++it) {
    int i = tid + it * 256;
    int row = i >> 5, c4 = i & 31;
    int s2 = selLds[row];
    float4 q = *(const float4*)(emb + (size_t)s2 * KDIM + c4 * 4);
    *(float4*)(out + (size_t)(gR0 + row) * KDIM + c4 * 4) = q;
  }
}

// ---- deterministic loss reduction over 512 block partials ----
__global__ void vq_reduce(const float* __restrict__ p, float* __restrict__ loss) {
  int t = threadIdx.x;
  double s = (double)p[t] + (double)p[t + 256];
#pragma unroll
  for (int m = 1; m <= 32; m <<= 1) s += __shfl_xor(s, m);
  __shared__ double w[4];
  if ((t & 63) == 0) w[t >> 6] = s;
  __syncthreads();
  if (t == 0) loss[0] = (float)((w[0] + w[1] + w[2] + w[3]) * (1.25 / 8388608.0));
}

extern "C" void kernel_launch(void* const* d_in, const int* in_sizes, int n_in,
                              void* d_out, int out_size, void* d_ws, size_t ws_size,
                              hipStream_t stream) {
  const float* lat = (const float*)d_in[0];   // [8192,1024] fp32
  const float* emb = (const float*)d_in[1];   // [1024,128]  fp32
  const int* ksel = (const int*)d_in[2];      // [8] int32
  float* out = (float*)d_out;                 // quantized[8388608] + loss[1]

  ushort* ebf = (ushort*)d_ws;                          // 262144 B (swizzled bf16 codes)
  float* esqm = (float*)((char*)d_ws + 262144);         // 4096 B (-0.5*||e||^2)
  float* partial = (float*)((char*)d_ws + 266240);      // 2048 B

  vq_prep<<<1024, 128, 0, stream>>>(emb, ebf, esqm);
  vq_main<<<512, 256, 0, stream>>>(lat, emb, ksel, ebf, esqm, out, partial);
  vq_reduce<<<1, 256, 0, stream>>>(partial, out + NELEM);
}

// Round 6
// 44.530 us; speedup vs baseline: 1.4061x; 1.0318x over previous
//
#include <hip/hip_runtime.h>

#define KDIM   128
#define NELEM  8388608

// LDS layout (bytes):
// [0,65536)      ebuf dbuf 2 x 32768 (codes, swizzled)   | mbuf f32[128][36] aliases after loop
// [65536,69632)  esqmLds f32[1024]  (-0.5*||e||^2)
// [69632,70144)  fsqLds f32[128]
// [70144,70656)  selLds i32[128]
// [70656,70664)  redL f32[2]
#define OFF_EBUF 0
#define OFF_ESQ  65536
#define OFF_FSQ  69632
#define OFF_SEL  70144
#define OFF_RED  70656
#define SMEM_SZ  70688

typedef __attribute__((ext_vector_type(8)))  short  short8;
typedef __attribute__((ext_vector_type(8)))  __bf16 bf16x8;
typedef __attribute__((ext_vector_type(4)))  float  f32x4;

__device__ inline ushort f2bf(float f) {            // RNE fp32 -> bf16
  unsigned u = __builtin_bit_cast(unsigned, f);
  u += 0x7fffu + ((u >> 16) & 1u);
  return (ushort)(u >> 16);
}
__device__ inline f32x4 mfma16(short8 a, short8 b, f32x4 c) {
  return __builtin_amdgcn_mfma_f32_16x16x32_bf16(
      __builtin_bit_cast(bf16x8, a), __builtin_bit_cast(bf16x8, b), c, 0, 0, 0);
}
__device__ inline void gload16(const void* g, void* l) {
  __builtin_amdgcn_global_load_lds(
      (const __attribute__((address_space(1))) unsigned*)g,
      (__attribute__((address_space(3))) unsigned*)l, 16, 0, 0);
}

// ---- prep: embedding fp32 -> bf16 (K-XOR-swizzled) + per-code -0.5*||e||^2 ----
__global__ void vq_prep(const float* __restrict__ emb, ushort* __restrict__ ebf,
                        float* __restrict__ esqm) {
  int j = blockIdx.x, d = threadIdx.x;              // 1024 x 128
  float v = emb[j * KDIM + d];
  ebf[j * KDIM + (d ^ ((j & 7) << 3))] = f2bf(v);   // elem-XOR == byte ^ ((row&7)<<4)
  float s = v * v;
#pragma unroll
  for (int m = 1; m <= 32; m <<= 1) s += __shfl_xor(s, m);
  __shared__ float w[2];
  if ((threadIdx.x & 63) == 0) w[threadIdx.x >> 6] = s;
  __syncthreads();
  if (threadIdx.x == 0) esqm[j] = -0.5f * (w[0] + w[1]);
}

// ---- main: 8 chunks x 128 codes, 1 barrier/chunk, latents direct-to-reg ----
__global__ __launch_bounds__(256, 2) void vq_main(
    const float* __restrict__ lat, const float* __restrict__ emb,
    const int* __restrict__ ksel, const ushort* __restrict__ ebf,
    const float* __restrict__ esqm, float* __restrict__ out,
    float* __restrict__ partial) {
  __shared__ __align__(16) unsigned char smem[SMEM_SZ];
  float* esqmLds = (float*)(smem + OFF_ESQ);
  float* fsqLds  = (float*)(smem + OFF_FSQ);
  int*   selLds  = (int*)(smem + OFF_SEL);
  float* redL    = (float*)(smem + OFF_RED);
  float* mbuf    = (float*)(smem + OFF_EBUF);       // alias, used after loop

  const int tid = threadIdx.x;
  const int lane = tid & 63, wid = tid >> 6;
  const int gR0 = blockIdx.x * 128;
  const int n = lane & 15, hi = lane >> 4;

  // 1) chunk-0 DMA -> buf0 (ebf pre-swizzled; linear copy)
  {
    const char* src = (const char*)ebf + tid * 16;
    char* dst = (char*)smem + OFF_EBUF + tid * 16;
#pragma unroll
    for (int q = 0; q < 8; ++q) gload16(src + q * 4096, dst + q * 4096);
  }
  // 2) all 1024 pre-scaled code norms -> LDS
  ((float4*)esqmLds)[tid] = ((const float4*)esqm)[tid];

  // 3) latents: global -> B-frag registers directly (+ ||f||^2 partials)
  short8 bfr[2][4];
  float fsqp[2];
#pragma unroll
  for (int ct = 0; ct < 2; ++ct) {
    const float* rp = lat + (size_t)(gR0 + wid * 32 + ct * 16 + n) * KDIM + hi * 8;
    float s = 0.f;
#pragma unroll
    for (int sfr = 0; sfr < 4; ++sfr) {
      float4 v0 = *(const float4*)(rp + sfr * 32);
      float4 v1 = *(const float4*)(rp + sfr * 32 + 4);
      s += v0.x * v0.x + v0.y * v0.y + v0.z * v0.z + v0.w * v0.w
         + v1.x * v1.x + v1.y * v1.y + v1.z * v1.z + v1.w * v1.w;
      short8 b;
      b[0] = (short)f2bf(v0.x); b[1] = (short)f2bf(v0.y);
      b[2] = (short)f2bf(v0.z); b[3] = (short)f2bf(v0.w);
      b[4] = (short)f2bf(v1.x); b[5] = (short)f2bf(v1.y);
      b[6] = (short)f2bf(v1.z); b[7] = (short)f2bf(v1.w);
      bfr[ct][sfr] = b;
    }
    fsqp[ct] = s;
  }
#pragma unroll
  for (int ct = 0; ct < 2; ++ct) {
    float s = fsqp[ct];
    s += __shfl_xor(s, 16);
    s += __shfl_xor(s, 32);
    if (hi == 0) fsqLds[wid * 32 + ct * 16 + n] = s;
  }
  asm volatile("s_waitcnt vmcnt(0)" ::: "memory");   // chunk-0 DMA + latent loads done
  __syncthreads();                                   // esqm/fsq ds_writes visible; buf0 ready

  // A-read bases (swizzled): byte = n*256 + [(s*64+hi*16) ^ ((n&7)<<4)] + tp*4096
  const int nm = n & 7;
  const int pb = ((hi ^ (nm & 3)) << 4) | (((nm >> 2) & 1) << 6);
  const char* aE0 = (const char*)smem + OFF_EBUF + n * 256 + pb;
  const char* aO0 = (const char*)smem + OFF_EBUF + n * 256 + (pb ^ 64);

  int cidx[4];
#pragma unroll
  for (int r = 0; r < 4; ++r) cidx[r] = hi * 4 + r;   // grows +16 per tile -> 0..1023

  const float NINF = __builtin_bit_cast(float, 0xFF800000u);
  float top[2][8];
#pragma unroll
  for (int ct = 0; ct < 2; ++ct)
#pragma unroll
    for (int p = 0; p < 8; ++p) top[ct][p] = NINF;
  float kq[2][4];                                     // even-tile packed keys

#pragma unroll 2
  for (int nn = 0; nn < 8; ++nn) {
    const int cb = (nn & 1) * 32768;
    if (nn < 7) {   // issue next-chunk DMA; lands during this chunk's compute
      const char* src = (const char*)ebf + (nn + 1) * 32768 + tid * 16;
      char* dst = (char*)smem + OFF_EBUF + (((nn + 1) & 1) * 32768) + tid * 16;
#pragma unroll
      for (int q = 0; q < 8; ++q) gload16(src + q * 4096, dst + q * 4096);
    }
    const float* eqb = esqmLds + nn * 128 + hi * 4;
#pragma unroll
    for (int tp = 0; tp < 8; ++tp) {
      f32x4 e = *(const f32x4*)(eqb + tp * 16);
      f32x4 acc0 = e, acc1 = e;       // init = -0.5*||e||^2 -> final = f.e - ||e||^2/2
#pragma unroll
      for (int s = 0; s < 4; ++s) {
        const char* ab = ((s & 1) ? aO0 : aE0) + cb + tp * 4096 + (s >> 1) * 128;
        short8 a = *(const short8*)ab;
        acc0 = mfma16(a, bfr[0][s], acc0);
        acc1 = mfma16(a, bfr[1][s], acc1);
      }
      // pack code id into low-10 mantissa bits
      float kn[2][4];
#pragma unroll
      for (int r = 0; r < 4; ++r) {
        kn[0][r] = __builtin_bit_cast(float,
            (__builtin_bit_cast(unsigned, acc0[r]) & 0xFFFFFC00u) | (unsigned)cidx[r]);
        kn[1][r] = __builtin_bit_cast(float,
            (__builtin_bit_cast(unsigned, acc1[r]) & 0xFFFFFC00u) | (unsigned)cidx[r]);
        cidx[r] += 16;
      }
      if ((tp & 1) == 0) {
#pragma unroll
        for (int ct = 0; ct < 2; ++ct)
#pragma unroll
          for (int r = 0; r < 4; ++r) kq[ct][r] = kn[ct][r];
      } else {
#pragma unroll
        for (int ct = 0; ct < 2; ++ct) {   // 8-code cell max -> top-8 insert
          float x = fmaxf(fmaxf(kq[ct][0], kq[ct][1]), fmaxf(kq[ct][2], kq[ct][3]));
          float y = fmaxf(fmaxf(kn[ct][0], kn[ct][1]), fmaxf(kn[ct][2], kn[ct][3]));
          float key = fmaxf(x, y);
#pragma unroll
          for (int p = 0; p < 8; ++p) {    // descending top-8, branchless
            float mx = fmaxf(top[ct][p], key);
            key = fminf(top[ct][p], key);
            top[ct][p] = mx;
          }
        }
      }
    }
    if (nn < 7) {
      asm volatile("s_waitcnt vmcnt(0)" ::: "memory");  // next chunk landed (issued ~1000cy ago)
      __builtin_amdgcn_s_barrier();                     // everyone done reading cur + next ready
    }
  }

  __syncthreads();   // all chunk reads done -> mbuf may overwrite ebuf

  // dump: row L gets 4 lists (hi), slot XOR'd by n&3; row stride 36 floats
#pragma unroll
  for (int ct = 0; ct < 2; ++ct) {
    const int L = wid * 32 + ct * 16 + n;
    const int sl = hi ^ (n & 3);
    float* dst = mbuf + L * 36 + sl * 8;
    *(f32x4*)(dst + 0) = (f32x4){top[ct][0], top[ct][1], top[ct][2], top[ct][3]};
    *(f32x4*)(dst + 4) = (f32x4){top[ct][4], top[ct][5], top[ct][6], top[ct][7]};
  }
  __syncthreads();

  // merge 4 sorted lists per row, pick k-th (keys unique via id bits)
  if (tid < 128) {
    const int L = tid, xk = L & 3;
    int kk = ksel[L & 7]; kk = kk < 0 ? 0 : (kk > 7 ? 7 : kk);
    float hh[4]; int ix[4];
#pragma unroll
    for (int j = 0; j < 4; ++j) { hh[j] = mbuf[L * 36 + ((j ^ xk) << 3)]; ix[j] = 0; }
    float sel;
    for (int s = 0;; ++s) {
      sel = fmaxf(fmaxf(hh[0], hh[1]), fmaxf(hh[2], hh[3]));
      if (s == kk) break;
#pragma unroll
      for (int j = 0; j < 4; ++j) {
        if (hh[j] == sel) {
          ++ix[j];
          hh[j] = (ix[j] < 8) ? mbuf[L * 36 + ((j ^ xk) << 3) + ix[j]] : NINF;
        }
      }
    }
    unsigned sb = __builtin_bit_cast(unsigned, sel);
    selLds[L] = (int)(sb & 1023u);
    // row loss = ||f||^2 - 2*(f.e - ||e||^2/2) = ||q - f||^2
    float val = __builtin_bit_cast(float, sb & 0xFFFFFC00u);
    float rl = fsqLds[L] - 2.0f * val;
#pragma unroll
    for (int m = 1; m <= 32; m <<= 1) rl += __shfl_xor(rl, m);
    if (lane == 0) redL[wid] = rl;
  }
  __syncthreads();
  if (tid == 0) partial[blockIdx.x] = redL[0] + redL[1];

  // epilogue: gather selected fp32 code rows -> out (coalesced; emb L2-hot)
#pragma unroll
  for (int it = 0; it < 16; ++it) {
    int i = tid + it * 256;
    int row = i >> 5, c4 = i & 31;
    int s2 = selLds[row];
    float4 q = *(const float4*)(emb + (size_t)s2 * KDIM + c4 * 4);
    *(float4*)(out + (size_t)(gR0 + row) * KDIM + c4 * 4) = q;
  }
}

// ---- deterministic loss reduction over 512 block partials ----
__global__ void vq_reduce(const float* __restrict__ p, float* __restrict__ loss) {
  int t = threadIdx.x;
  double s = (double)p[t] + (double)p[t + 256];
#pragma unroll
  for (int m = 1; m <= 32; m <<= 1) s += __shfl_xor(s, m);
  __shared__ double w[4];
  if ((t & 63) == 0) w[t >> 6] = s;
  __syncthreads();
  if (t == 0) loss[0] = (float)((w[0] + w[1] + w[2] + w[3]) * (1.25 / 8388608.0));
}

extern "C" void kernel_launch(void* const* d_in, const int* in_sizes, int n_in,
                              void* d_out, int out_size, void* d_ws, size_t ws_size,
                              hipStream_t stream) {
  const float* lat = (const float*)d_in[0];   // [8192,1024] fp32
  const float* emb = (const float*)d_in[1];   // [1024,128]  fp32
  const int* ksel = (const int*)d_in[2];      // [8] int32
  float* out = (float*)d_out;                 // quantized[8388608] + loss[1]

  ushort* ebf = (ushort*)d_ws;                          // 262144 B (swizzled bf16 codes)
  float* esqm = (float*)((char*)d_ws + 262144);         // 4096 B (-0.5*||e||^2)
  float* partial = (float*)((char*)d_ws + 266240);      // 2048 B

  vq_prep<<<1024, 128, 0, stream>>>(emb, ebf, esqm);
  vq_main<<<512, 256, 0, stream>>>(lat, emb, ksel, ebf, esqm, out, partial);
  vq_reduce<<<1, 256, 0, stream>>>(partial, out + NELEM);
}